// Round 15
// baseline (168.354 us; speedup 1.0000x reference)
//
#include <hip/hip_runtime.h>

// ---------------------------------------------------------------------------
// MultiheadAttention forward: B=2 T=2048 E=1024 H=16 D=64, fp32 in/out.
// Round-9 pipeline with casts fused into gemm3: gemm3 reg-stages fp32
// operands (float4x2 -> cvt_pk -> ds_write_b128) into the SAME swizzled
// bf16 LDS image; MFMA loop + epilogues unchanged. Wo keeps a small cast.
// attn = round-9 verbatim (best passing, 81 us). gemm_out unchanged.
// ---------------------------------------------------------------------------

typedef __attribute__((ext_vector_type(8))) short s8v;
typedef __attribute__((ext_vector_type(4))) float f4v;

typedef __attribute__((address_space(1))) const void* gas_t;
typedef __attribute__((address_space(3))) void* las_t;

#define GLOAD_LDS(src, dst) \
  __builtin_amdgcn_global_load_lds((gas_t)(src), (las_t)(dst), 16, 0, 0)
#define MFMA16(a, b, c) __builtin_amdgcn_mfma_f32_16x16x32_bf16((a), (b), (c), 0, 0, 0)

#if __has_builtin(__builtin_amdgcn_exp2f)
#define EXP2(x) __builtin_amdgcn_exp2f(x)
#else
#define EXP2(x) exp2f(x)
#endif

static constexpr int Bn = 2, Tn = 2048, En = 1024, Hn = 16, Dn = 64;
static constexpr float kScale = 0.125f;  // 1/sqrt(64)
static constexpr float kLog2e = 1.4426950408889634f;

union P8 { s8v v; unsigned short u[8]; };

__device__ __forceinline__ unsigned short f2bf(float f) {
  unsigned int x = __float_as_uint(f);
  x += 0x7fffu + ((x >> 16) & 1u);  // RNE; inputs finite
  return (unsigned short)(x >> 16);
}

__device__ __forceinline__ int cvtpk(float lo, float hi) {
  int r;
  asm("v_cvt_pk_bf16_f32 %0, %1, %2" : "=v"(r) : "v"(lo), "v"(hi));
  return r;
}

// ---------------- cast for Wo only --------------------------------------
__global__ void cast1_kernel(const float* __restrict__ in,
                             unsigned short* __restrict__ out, int n8) {
  int i = blockIdx.x * blockDim.x + threadIdx.x;
  const int stride = gridDim.x * blockDim.x;
  for (; i < n8; i += stride) {
    float4 a = ((const float4*)in)[2 * i];
    float4 b = ((const float4*)in)[2 * i + 1];
    P8 p;
    p.u[0] = f2bf(a.x); p.u[1] = f2bf(a.y); p.u[2] = f2bf(a.z); p.u[3] = f2bf(a.w);
    p.u[4] = f2bf(b.x); p.u[5] = f2bf(b.y); p.u[6] = f2bf(b.z); p.u[7] = f2bf(b.w);
    ((s8v*)out)[i] = p.v;
  }
}

// ---------------- mask pre-pack: bf16 pairs in MFMA-C order, * log2e --------
__global__ __launch_bounds__(64) void maskpack_kernel(const float* __restrict__ mask,
                                                      unsigned int* __restrict__ mPB) {
  __shared__ float tile[16][65];
  const int qt = blockIdx.x, st = blockIdx.y;  // [0,128) x [0,32)
  const int tid = threadIdx.x;
#pragma unroll
  for (int i = 0; i < 16; ++i)
    tile[i][tid] = mask[(size_t)(qt * 16 + i) * Tn + st * 64 + tid];
  __syncthreads();
  const int lr = tid & 15, lg = tid >> 4;
  float o[16];
#pragma unroll
  for (int n = 0; n < 4; ++n)
#pragma unroll
    for (int rg = 0; rg < 4; ++rg)
      o[n * 4 + rg] = tile[lr][n * 16 + lg * 4 + rg] * kLog2e;
  unsigned int wds[8];
#pragma unroll
  for (int i = 0; i < 8; ++i)
    wds[i] = ((unsigned int)f2bf(o[2 * i + 1]) << 16) | f2bf(o[2 * i]);
  uint4* dst = (uint4*)(mPB + ((size_t)(qt * 32 + st) * 64 + tid) * 8);
  dst[0] = make_uint4(wds[0], wds[1], wds[2], wds[3]);
  dst[1] = make_uint4(wds[4], wds[5], wds[6], wds[7]);
}

// ---------------- fused projection GEMM, fp32 inputs (cast fused) -----------
// z=0: C=query*Wq^T -> Qh [B,H,T,D] (*scale); z=1: key_*Wk^T -> Kh;
// z=2: C=Wv*value^T -> Vtg [B,H,D,S].  Reg-staged fp32 -> bf16 LDS image
// identical to the verified gload_lds layout: LDS(r,c) = G(r, c^(r&7)).
__global__ __launch_bounds__(256) void gemm3_kernel(
    const float* __restrict__ query, const float* __restrict__ key_,
    const float* __restrict__ value, const float* __restrict__ Wq,
    const float* __restrict__ Wk, const float* __restrict__ Wv,
    unsigned short* __restrict__ Qh, unsigned short* __restrict__ Kh,
    unsigned short* __restrict__ Vtg) {
  constexpr int K = 1024;
  __shared__ unsigned short As[128 * 64];
  __shared__ unsigned short Bs[128 * 64];
  const int tid = threadIdx.x;
  const int w = tid >> 6, l = tid & 63;
  const int wr = w >> 1, wc = w & 1;
  const int lr = l & 15, lg = l >> 4;

  const int id0 = blockIdx.x;
  const int rid = (id0 & 7) * 96 + (id0 >> 3);
  const int z = rid >> 8;             // 0,1,2
  const int t8 = rid & 255;
  const int m0 = (z < 2) ? (t8 >> 3) * 128 : (t8 & 7) * 128;
  const int n0 = (z < 2) ? (t8 & 7) * 128 : (t8 >> 3) * 128;

  const float* A = (z == 0) ? query : (z == 1) ? key_ : Wv;
  const float* W = (z == 0) ? Wq : (z == 1) ? Wk : value;

  // reg-stage one 128x64 fp32 tile -> bf16 swizzled LDS image
  auto stage = [&](const float* src, int baseRow, int k0, unsigned short* lds) {
#pragma unroll
    for (int jj = 0; jj < 4; ++jj) {
      const int q = jj * 256 + tid;
      const int r = q >> 3, c = q & 7;
      const float4* g =
          (const float4*)(src + (size_t)(baseRow + r) * K + k0 + c * 8);
      const float4 a = g[0], b4 = g[1];
      union { int x[4]; s8v v; } pk;
      pk.x[0] = cvtpk(a.x, a.y);
      pk.x[1] = cvtpk(a.z, a.w);
      pk.x[2] = cvtpk(b4.x, b4.y);
      pk.x[3] = cvtpk(b4.z, b4.w);
      *(s8v*)((char*)lds + ((q & ~7) + (c ^ (r & 7))) * 16) = pk.v;
    }
  };

  f4v acc[4][4] = {};

  for (int k0 = 0; k0 < K; k0 += 64) {
    stage(A, m0, k0, As);
    stage(W, n0, k0, Bs);
    __syncthreads();
#pragma unroll
    for (int kk = 0; kk < 2; ++kk) {
      s8v af[4], bf[4];
      const int kc = kk * 4 + lg;
#pragma unroll
      for (int i = 0; i < 4; ++i) {
        const int ra = wr * 64 + i * 16 + lr;
        const int rb = wc * 64 + i * 16 + lr;
        af[i] = *(const s8v*)((const char*)As + ra * 128 + ((kc ^ (ra & 7)) << 4));
        bf[i] = *(const s8v*)((const char*)Bs + rb * 128 + ((kc ^ (rb & 7)) << 4));
      }
#pragma unroll
      for (int mi = 0; mi < 4; ++mi)
#pragma unroll
        for (int nj = 0; nj < 4; ++nj)
          acc[mi][nj] = MFMA16(af[mi], bf[nj], acc[mi][nj]);
    }
    __syncthreads();
  }

  const float scale = (z == 0) ? kScale * kLog2e : 1.0f;
#pragma unroll
  for (int mi = 0; mi < 4; ++mi)
#pragma unroll
    for (int nj = 0; nj < 4; ++nj)
#pragma unroll
      for (int rg = 0; rg < 4; ++rg) {
        const int row = m0 + wr * 64 + mi * 16 + lg * 4 + rg;
        const int col = n0 + wc * 64 + nj * 16 + lr;
        const float v = acc[mi][nj][rg];
        if (z < 2) {
          const int b = row >> 11, t = row & (Tn - 1);
          const int hh = col >> 6, d = col & 63;
          unsigned short* o = (z == 0) ? Qh : Kh;
          o[(((size_t)(b * Hn + hh) * Tn + t) << 6) + d] = f2bf(v * scale);
        } else {
          const int hh = row >> 6, d = row & 63;
          const int b = col >> 11, t = col & (Tn - 1);
          Vtg[((size_t)(b * Hn + hh) * 64 + d) * Tn + t] = f2bf(v);
        }
      }
}

// ---------------- out-proj GEMM: fp32 out, double-buffered (r9 verbatim) ----
__global__ __launch_bounds__(256) void gemm_out(const unsigned short* __restrict__ A,
                                                const unsigned short* __restrict__ W,
                                                float* __restrict__ Cout) {
  constexpr int N = 1024, K = 1024;
  __shared__ unsigned short As[2][128 * 64];
  __shared__ unsigned short Bs[2][128 * 64];
  const int tid = threadIdx.x;
  const int w = tid >> 6, l = tid & 63;
  const int wr = w >> 1, wc = w & 1;
  const int lr = l & 15, lg = l >> 4;

  const int gx = gridDim.x;
  int id = blockIdx.y * gx + blockIdx.x;
  id = (id & 7) * 32 + (id >> 3);
  const int m0 = (id / gx) * 128, n0 = (id % gx) * 128;

  auto stage = [&](int k0, int buf) {
#pragma unroll
    for (int jj = 0; jj < 4; ++jj) {
      const int q = jj * 256 + tid;
      const int r = q >> 3, c = q & 7;
      const int cs = c ^ (r & 7);
      GLOAD_LDS(A + (size_t)(m0 + r) * K + k0 + cs * 8,
                (char*)As[buf] + (jj * 256 + w * 64) * 16);
      GLOAD_LDS(W + (size_t)(n0 + r) * K + k0 + cs * 8,
                (char*)Bs[buf] + (jj * 256 + w * 64) * 16);
    }
  };

  stage(0, 0);
  __syncthreads();

  f4v acc[4][4] = {};

  for (int k0 = 0, t = 0; k0 < K; k0 += 64, ++t) {
    const int cur = t & 1;
    if (k0 + 64 < K) stage(k0 + 64, cur ^ 1);
#pragma unroll
    for (int kk = 0; kk < 2; ++kk) {
      s8v af[4], bf[4];
      const int kc = kk * 4 + lg;
#pragma unroll
      for (int i = 0; i < 4; ++i) {
        const int ra = wr * 64 + i * 16 + lr;
        const int rb = wc * 64 + i * 16 + lr;
        af[i] = *(const s8v*)((const char*)As[cur] + ra * 128 + ((kc ^ (ra & 7)) << 4));
        bf[i] = *(const s8v*)((const char*)Bs[cur] + rb * 128 + ((kc ^ (rb & 7)) << 4));
      }
#pragma unroll
      for (int mi = 0; mi < 4; ++mi)
#pragma unroll
        for (int nj = 0; nj < 4; ++nj)
          acc[mi][nj] = MFMA16(af[mi], bf[nj], acc[mi][nj]);
    }
    __syncthreads();
  }

#pragma unroll
  for (int mi = 0; mi < 4; ++mi)
#pragma unroll
    for (int nj = 0; nj < 4; ++nj)
#pragma unroll
      for (int rg = 0; rg < 4; ++rg) {
        const int row = m0 + wr * 64 + mi * 16 + lg * 4 + rg;
        const int col = n0 + wc * 64 + nj * 16 + lr;
        Cout[(size_t)row * N + col] = acc[mi][nj][rg];
      }
}

// ---------------- Flash attention: round-9 verbatim -------------------------
__global__ __launch_bounds__(256, 4) void attn_kernel(
    const unsigned short* __restrict__ Q,    // [B,H,T,D], pre-scaled
    const unsigned short* __restrict__ Kg,   // [B,H,T,D]
    const unsigned short* __restrict__ Vt,   // [B,H,D,S]
    const unsigned int* __restrict__ mPB,    // packed bf16 mask
    unsigned short* __restrict__ Out) {      // [B,T,H,D]
  __shared__ unsigned short Ks[2][64 * 64];  // [s][d], XOR-swizzled chunks
  __shared__ unsigned short Vs[2][64 * 64];  // [d][s], XOR-swizzled chunks

  const int tid = threadIdx.x;
  const int w = tid >> 6, lane = tid & 63;
  const int lr = lane & 15, lg = lane >> 4;

  const int lin = blockIdx.x;
  const int xcd = lin & 7, slot = lin >> 3;   // slot in [0,128)
  const int bh = xcd * 4 + (slot >> 5);
  const int qtB = slot & 31;                  // q-tile of 64 rows
  const int b = bh >> 4, h = bh & 15;

  const size_t hoff = (size_t)bh * Tn * Dn;
  const unsigned short* Qh = Q + hoff;
  const unsigned short* Kh = Kg + hoff;
  const unsigned short* Vh = Vt + hoff;
  const int qw = qtB * 64 + w * 16;
  const unsigned int* mp = mPB + ((size_t)(qtB * 4 + w) * 2048 + lane) * 8;

  auto stage = [&](int s0, int buf) {
#pragma unroll
    for (int jj = 0; jj < 2; ++jj) {
      const int cq = jj * 256 + tid;
      const int r = cq >> 3, cc = cq & 7;
      const int cs = cc ^ (r & 7);
      GLOAD_LDS(Kh + (size_t)(s0 + r) * 64 + cs * 8,
                (char*)Ks[buf] + (jj * 256 + w * 64) * 16);
      GLOAD_LDS(Vh + (size_t)r * Tn + s0 + cs * 8,
                (char*)Vs[buf] + (jj * 256 + w * 64) * 16);
    }
  };

  // Q fragments (B-operand of swapped QK^T): Q[qw+lr][kk*32 + lg*8 + e]
  s8v qf[2];
#pragma unroll
  for (int kk = 0; kk < 2; ++kk)
    qf[kk] = *(const s8v*)(Qh + (size_t)(qw + lr) * 64 + kk * 32 + lg * 8);

  float lsum = 0.f;
  f4v oacc[4] = {};

  const int srcA = lr + ((lg & 1) << 5);
  const int srcB = srcA + 16;
  const int hi = lg >> 1;

  stage(0, 0);
  __syncthreads();

  for (int s0 = 0, t = 0; s0 < Tn; s0 += 64, ++t, mp += 512) {
    const int cur = t & 1;
    if (s0 + 64 < Tn) stage(s0 + 64, cur ^ 1);

    // C-init = packed bf16 mask (already *log2e)
    const uint4 u0 = *(const uint4*)(mp);
    const uint4 u1 = *(const uint4*)(mp + 4);
    const unsigned int wd[8] = {u0.x, u0.y, u0.z, u0.w, u1.x, u1.y, u1.z, u1.w};
    f4v scT[4];
#pragma unroll
    for (int n = 0; n < 4; ++n) {
      scT[n][0] = __uint_as_float(wd[2 * n] << 16);
      scT[n][1] = __uint_as_float(wd[2 * n] & 0xffff0000u);
      scT[n][2] = __uint_as_float(wd[2 * n + 1] << 16);
      scT[n][3] = __uint_as_float(wd[2 * n + 1] & 0xffff0000u);
    }

    // swapped QK^T from LDS
#pragma unroll
    for (int kk = 0; kk < 2; ++kk)
#pragma unroll
      for (int n = 0; n < 4; ++n) {
        const int row = n * 16 + lr;
        s8v kf = *(const s8v*)((const char*)Ks[cur] + row * 128 +
                               (((kk * 4 + lg) ^ (lr & 7)) << 4));
        scT[n] = MFMA16(kf, qf[kk], scT[n]);
      }

    // shift-free softmax numerator; row sum over 4 lanes (stride 16)
    float ssum = 0.f;
#pragma unroll
    for (int n = 0; n < 4; ++n)
#pragma unroll
      for (int rg = 0; rg < 4; ++rg) {
        const float p = EXP2(scT[n][rg]);
        scT[n][rg] = p;
        ssum += p;
      }
    ssum += __shfl_xor(ssum, 16);
    ssum += __shfl_xor(ssum, 32);
    lsum += ssum;

    // pack P^T to bf16 pair-words
    int pw0[4], pw1[4];
#pragma unroll
    for (int n = 0; n < 4; ++n) {
      pw0[n] = cvtpk(scT[n][0], scT[n][1]);
      pw1[n] = cvtpk(scT[n][2], scT[n][3]);
    }

    // PV: O += P * V (A-frag assembled via shfl, verified slot math)
#pragma unroll
    for (int kk = 0; kk < 2; ++kk) {
      const int a0 = __shfl(pw0[2 * kk], srcA), b0 = __shfl(pw0[2 * kk + 1], srcA);
      const int a1 = __shfl(pw1[2 * kk], srcA), b1 = __shfl(pw1[2 * kk + 1], srcA);
      const int a2 = __shfl(pw0[2 * kk], srcB), b2 = __shfl(pw0[2 * kk + 1], srcB);
      const int a3 = __shfl(pw1[2 * kk], srcB), b3 = __shfl(pw1[2 * kk + 1], srcB);
      union { s8v v; int x[4]; } pf;
      pf.x[0] = hi ? b0 : a0;
      pf.x[1] = hi ? b1 : a1;
      pf.x[2] = hi ? b2 : a2;
      pf.x[3] = hi ? b3 : a3;
#pragma unroll
      for (int n = 0; n < 4; ++n) {
        const int rd = n * 16 + lr;
        s8v vf = *(const s8v*)((const char*)Vs[cur] + rd * 128 +
                               (((kk * 4 + lg) ^ (lr & 7)) << 4));
        oacc[n] = MFMA16(pf.v, vf, oacc[n]);
      }
    }
    __syncthreads();  // drains next-tile stage + guards buffer reuse
  }

  // epilogue: O / lsum(q), write bf16 [B,T,H,D]
#pragma unroll
  for (int rg = 0; rg < 4; ++rg) {
    const float inv = 1.f / __shfl(lsum, lg * 4 + rg);
    const int t = qw + lg * 4 + rg;
#pragma unroll
    for (int n = 0; n < 4; ++n) {
      const int d = n * 16 + lr;
      Out[((size_t)(b * Tn + t) * Hn + h) * 64 + d] = f2bf(oacc[n][rg] * inv);
    }
  }
}

// ---------------------------------------------------------------------------
extern "C" void kernel_launch(void* const* d_in, const int* in_sizes, int n_in,
                              void* d_out, int out_size, void* d_ws, size_t ws_size,
                              hipStream_t stream) {
  (void)in_sizes; (void)n_in; (void)out_size; (void)ws_size;
  const float* query = (const float*)d_in[0];
  const float* key_  = (const float*)d_in[1];
  const float* value = (const float*)d_in[2];
  const float* mask  = (const float*)d_in[3];
  const float* Wq    = (const float*)d_in[4];
  const float* Wk    = (const float*)d_in[5];
  const float* Wv    = (const float*)d_in[6];
  const float* Wo    = (const float*)d_in[7];
  float* out = (float*)d_out;

  char* ws = (char*)d_ws;
  const size_t MB = 1024 * 1024;
  unsigned int*   mPB = (unsigned int*)(ws + 0 * MB);     // 8.4 MB packed mask
  unsigned short* Qh  = (unsigned short*)(ws + 24 * MB);  // [B,H,T,D] (pre-scaled)
  unsigned short* Kh  = (unsigned short*)(ws + 32 * MB);  // [B,H,T,D]
  unsigned short* Vtg = (unsigned short*)(ws + 40 * MB);  // [B,H,D,S]
  unsigned short* atb = (unsigned short*)(ws + 48 * MB);  // [B,T,H,D]
  unsigned short* wox = (unsigned short*)(ws + 62 * MB);  // Wo bf16

  const int nW = En * En / 8;  // 131072
  maskpack_kernel<<<dim3(128, 32), 64, 0, stream>>>(mask, mPB);
  cast1_kernel<<<512, 256, 0, stream>>>(Wo, wox, nW);

  gemm3_kernel<<<768, 256, 0, stream>>>(query, key_, value, Wq, Wk, Wv,
                                        Qh, Kh, Vtg);

  attn_kernel<<<1024, 256, 0, stream>>>(Qh, Kh, Vtg, mPB, atb);

  gemm_out<<<dim3(8, 32), 256, 0, stream>>>(atb, wox, out);
}

// Round 16
// 158.780 us; speedup vs baseline: 1.0603x; 1.0603x over previous
//
#include <hip/hip_runtime.h>

// ---------------------------------------------------------------------------
// MultiheadAttention forward: B=2 T=2048 E=1024 H=16 D=64, fp32 in/out.
// Round-9 pipeline verbatim (best passing, 160.2 us) with one delta:
// cast3+cast4 merged into a single grid-stride cast7 launch (7->5 launches).
// ---------------------------------------------------------------------------

typedef __attribute__((ext_vector_type(8))) short s8v;
typedef __attribute__((ext_vector_type(4))) float f4v;

typedef __attribute__((address_space(1))) const void* gas_t;
typedef __attribute__((address_space(3))) void* las_t;

#define GLOAD_LDS(src, dst) \
  __builtin_amdgcn_global_load_lds((gas_t)(src), (las_t)(dst), 16, 0, 0)
#define MFMA16(a, b, c) __builtin_amdgcn_mfma_f32_16x16x32_bf16((a), (b), (c), 0, 0, 0)

#if __has_builtin(__builtin_amdgcn_exp2f)
#define EXP2(x) __builtin_amdgcn_exp2f(x)
#else
#define EXP2(x) exp2f(x)
#endif

static constexpr int Bn = 2, Tn = 2048, En = 1024, Hn = 16, Dn = 64;
static constexpr float kScale = 0.125f;  // 1/sqrt(64)
static constexpr float kLog2e = 1.4426950408889634f;

union P8 { s8v v; unsigned short u[8]; };

__device__ __forceinline__ unsigned short f2bf(float f) {
  unsigned int x = __float_as_uint(f);
  x += 0x7fffu + ((x >> 16) & 1u);  // RNE; inputs finite
  return (unsigned short)(x >> 16);
}

__device__ __forceinline__ int cvtpk(float lo, float hi) {
  int r;
  asm("v_cvt_pk_bf16_f32 %0, %1, %2" : "=v"(r) : "v"(lo), "v"(hi));
  return r;
}

__device__ __forceinline__ void cast8(const float* __restrict__ src, int j,
                                      unsigned short* __restrict__ out, int i) {
  float4 a = ((const float4*)src)[2 * j];
  float4 b = ((const float4*)src)[2 * j + 1];
  P8 p;
  p.u[0] = f2bf(a.x); p.u[1] = f2bf(a.y); p.u[2] = f2bf(a.z); p.u[3] = f2bf(a.w);
  p.u[4] = f2bf(b.x); p.u[5] = f2bf(b.y); p.u[6] = f2bf(b.z); p.u[7] = f2bf(b.w);
  ((s8v*)out)[i] = p.v;
}

// ---------------- fused cast: 3 activations + 4 weights, one launch ---------
// outA = qx/kx/vx contiguous (3*nBig chunks); outW = wqx..wox contiguous
// (4*nW chunks). Each chunk = 8 elements.
__global__ void cast7_kernel(const float* __restrict__ q, const float* __restrict__ k,
                             const float* __restrict__ v, const float* __restrict__ w0,
                             const float* __restrict__ w1, const float* __restrict__ w2,
                             const float* __restrict__ w3,
                             unsigned short* __restrict__ outA,
                             unsigned short* __restrict__ outW, int nBig, int nW) {
  int i = blockIdx.x * blockDim.x + threadIdx.x;
  const int stride = gridDim.x * blockDim.x;
  const int totA = 3 * nBig;
  const int total = totA + 4 * nW;
  for (; i < total; i += stride) {
    if (i < totA) {
      const float* src = (i < nBig) ? q : (i < 2 * nBig) ? k : v;
      const int j = (i < nBig) ? i : (i < 2 * nBig) ? i - nBig : i - 2 * nBig;
      cast8(src, j, outA, i);
    } else {
      const int jj = i - totA;
      const int which = jj / nW;
      const float* src = (which == 0) ? w0 : (which == 1) ? w1
                         : (which == 2) ? w2 : w3;
      cast8(src, jj - which * nW, outW, jj);
    }
  }
}

// ---------------- mask pre-pack: bf16 pairs in MFMA-C order, * log2e --------
__global__ __launch_bounds__(64) void maskpack_kernel(const float* __restrict__ mask,
                                                      unsigned int* __restrict__ mPB) {
  __shared__ float tile[16][65];
  const int qt = blockIdx.x, st = blockIdx.y;  // [0,128) x [0,32)
  const int tid = threadIdx.x;
#pragma unroll
  for (int i = 0; i < 16; ++i)
    tile[i][tid] = mask[(size_t)(qt * 16 + i) * Tn + st * 64 + tid];
  __syncthreads();
  const int lr = tid & 15, lg = tid >> 4;
  float o[16];
#pragma unroll
  for (int n = 0; n < 4; ++n)
#pragma unroll
    for (int rg = 0; rg < 4; ++rg)
      o[n * 4 + rg] = tile[lr][n * 16 + lg * 4 + rg] * kLog2e;
  unsigned int wds[8];
#pragma unroll
  for (int i = 0; i < 8; ++i)
    wds[i] = ((unsigned int)f2bf(o[2 * i + 1]) << 16) | f2bf(o[2 * i]);
  uint4* dst = (uint4*)(mPB + ((size_t)(qt * 32 + st) * 64 + tid) * 8);
  dst[0] = make_uint4(wds[0], wds[1], wds[2], wds[3]);
  dst[1] = make_uint4(wds[4], wds[5], wds[6], wds[7]);
}

// ---------------- fused projection GEMM (z=0:Q, z=1:K, z=2:V^T) -------------
// z<2: M=4096 (t-index) x N=1024 (h*64+d). z=2: M=1024 (h*64+d) x N=4096 (t).
__global__ __launch_bounds__(256) void gemm3_kernel(
    const unsigned short* __restrict__ qx, const unsigned short* __restrict__ kx,
    const unsigned short* __restrict__ vxa, const unsigned short* __restrict__ wqx,
    const unsigned short* __restrict__ wkx, const unsigned short* __restrict__ wvx,
    unsigned short* __restrict__ Qh, unsigned short* __restrict__ Kh,
    unsigned short* __restrict__ Vtg) {
  constexpr int K = 1024;
  __shared__ unsigned short As[128 * 64];
  __shared__ unsigned short Bs[128 * 64];
  const int tid = threadIdx.x;
  const int w = tid >> 6, l = tid & 63;
  const int wr = w >> 1, wc = w & 1;
  const int lr = l & 15, lg = l >> 4;

  const int id0 = blockIdx.x;
  const int rid = (id0 & 7) * 96 + (id0 >> 3);
  const int z = rid >> 8;             // 0,1,2
  const int t8 = rid & 255;
  const int m0 = (z < 2) ? (t8 >> 3) * 128 : (t8 & 7) * 128;
  const int n0 = (z < 2) ? (t8 & 7) * 128 : (t8 >> 3) * 128;

  const unsigned short* A = (z == 0) ? qx : (z == 1) ? kx : wvx;
  const unsigned short* W = (z == 0) ? wqx : (z == 1) ? wkx : vxa;

  f4v acc[4][4] = {};

  for (int k0 = 0; k0 < K; k0 += 64) {
#pragma unroll
    for (int jj = 0; jj < 4; ++jj) {
      const int q = jj * 256 + tid;
      const int r = q >> 3, c = q & 7;
      const int cs = c ^ (r & 7);
      GLOAD_LDS(A + (size_t)(m0 + r) * K + k0 + cs * 8,
                (char*)As + (jj * 256 + w * 64) * 16);
      GLOAD_LDS(W + (size_t)(n0 + r) * K + k0 + cs * 8,
                (char*)Bs + (jj * 256 + w * 64) * 16);
    }
    __syncthreads();
#pragma unroll
    for (int kk = 0; kk < 2; ++kk) {
      s8v af[4], bf[4];
      const int kc = kk * 4 + lg;
#pragma unroll
      for (int i = 0; i < 4; ++i) {
        const int ra = wr * 64 + i * 16 + lr;
        const int rb = wc * 64 + i * 16 + lr;
        af[i] = *(const s8v*)((const char*)As + ra * 128 + ((kc ^ (ra & 7)) << 4));
        bf[i] = *(const s8v*)((const char*)Bs + rb * 128 + ((kc ^ (rb & 7)) << 4));
      }
#pragma unroll
      for (int mi = 0; mi < 4; ++mi)
#pragma unroll
        for (int nj = 0; nj < 4; ++nj)
          acc[mi][nj] = MFMA16(af[mi], bf[nj], acc[mi][nj]);
    }
    __syncthreads();
  }

  const float scale = (z == 0) ? kScale * kLog2e : 1.0f;
#pragma unroll
  for (int mi = 0; mi < 4; ++mi)
#pragma unroll
    for (int nj = 0; nj < 4; ++nj)
#pragma unroll
      for (int rg = 0; rg < 4; ++rg) {
        const int row = m0 + wr * 64 + mi * 16 + lg * 4 + rg;
        const int col = n0 + wc * 64 + nj * 16 + lr;
        const float v = acc[mi][nj][rg];
        if (z < 2) {
          const int b = row >> 11, t = row & (Tn - 1);
          const int hh = col >> 6, d = col & 63;
          unsigned short* o = (z == 0) ? Qh : Kh;
          o[(((size_t)(b * Hn + hh) * Tn + t) << 6) + d] = f2bf(v * scale);
        } else {
          const int hh = row >> 6, d = row & 63;
          const int b = col >> 11, t = col & (Tn - 1);
          Vtg[((size_t)(b * Hn + hh) * 64 + d) * Tn + t] = f2bf(v);
        }
      }
}

// ---------------- out-proj GEMM: fp32 out, double-buffered ------------------
__global__ __launch_bounds__(256) void gemm_out(const unsigned short* __restrict__ A,
                                                const unsigned short* __restrict__ W,
                                                float* __restrict__ Cout) {
  constexpr int N = 1024, K = 1024;
  __shared__ unsigned short As[2][128 * 64];
  __shared__ unsigned short Bs[2][128 * 64];
  const int tid = threadIdx.x;
  const int w = tid >> 6, l = tid & 63;
  const int wr = w >> 1, wc = w & 1;
  const int lr = l & 15, lg = l >> 4;

  const int gx = gridDim.x;
  int id = blockIdx.y * gx + blockIdx.x;
  id = (id & 7) * 32 + (id >> 3);
  const int m0 = (id / gx) * 128, n0 = (id % gx) * 128;

  auto stage = [&](int k0, int buf) {
#pragma unroll
    for (int jj = 0; jj < 4; ++jj) {
      const int q = jj * 256 + tid;
      const int r = q >> 3, c = q & 7;
      const int cs = c ^ (r & 7);
      GLOAD_LDS(A + (size_t)(m0 + r) * K + k0 + cs * 8,
                (char*)As[buf] + (jj * 256 + w * 64) * 16);
      GLOAD_LDS(W + (size_t)(n0 + r) * K + k0 + cs * 8,
                (char*)Bs[buf] + (jj * 256 + w * 64) * 16);
    }
  };

  stage(0, 0);
  __syncthreads();

  f4v acc[4][4] = {};

  for (int k0 = 0, t = 0; k0 < K; k0 += 64, ++t) {
    const int cur = t & 1;
    if (k0 + 64 < K) stage(k0 + 64, cur ^ 1);
#pragma unroll
    for (int kk = 0; kk < 2; ++kk) {
      s8v af[4], bf[4];
      const int kc = kk * 4 + lg;
#pragma unroll
      for (int i = 0; i < 4; ++i) {
        const int ra = wr * 64 + i * 16 + lr;
        const int rb = wc * 64 + i * 16 + lr;
        af[i] = *(const s8v*)((const char*)As[cur] + ra * 128 + ((kc ^ (ra & 7)) << 4));
        bf[i] = *(const s8v*)((const char*)Bs[cur] + rb * 128 + ((kc ^ (rb & 7)) << 4));
      }
#pragma unroll
      for (int mi = 0; mi < 4; ++mi)
#pragma unroll
        for (int nj = 0; nj < 4; ++nj)
          acc[mi][nj] = MFMA16(af[mi], bf[nj], acc[mi][nj]);
    }
    __syncthreads();
  }

#pragma unroll
  for (int mi = 0; mi < 4; ++mi)
#pragma unroll
    for (int nj = 0; nj < 4; ++nj)
#pragma unroll
      for (int rg = 0; rg < 4; ++rg) {
        const int row = m0 + wr * 64 + mi * 16 + lg * 4 + rg;
        const int col = n0 + wc * 64 + nj * 16 + lr;
        Cout[(size_t)row * N + col] = acc[mi][nj][rg];
      }
}

// ---------------- Flash attention: round-9 verbatim -------------------------
__global__ __launch_bounds__(256, 4) void attn_kernel(
    const unsigned short* __restrict__ Q,    // [B,H,T,D], pre-scaled
    const unsigned short* __restrict__ Kg,   // [B,H,T,D]
    const unsigned short* __restrict__ Vt,   // [B,H,D,S]
    const unsigned int* __restrict__ mPB,    // packed bf16 mask
    unsigned short* __restrict__ Out) {      // [B,T,H,D]
  __shared__ unsigned short Ks[2][64 * 64];  // [s][d], XOR-swizzled chunks
  __shared__ unsigned short Vs[2][64 * 64];  // [d][s], XOR-swizzled chunks

  const int tid = threadIdx.x;
  const int w = tid >> 6, lane = tid & 63;
  const int lr = lane & 15, lg = lane >> 4;

  const int lin = blockIdx.x;
  const int xcd = lin & 7, slot = lin >> 3;   // slot in [0,128)
  const int bh = xcd * 4 + (slot >> 5);
  const int qtB = slot & 31;                  // q-tile of 64 rows
  const int b = bh >> 4, h = bh & 15;

  const size_t hoff = (size_t)bh * Tn * Dn;
  const unsigned short* Qh = Q + hoff;
  const unsigned short* Kh = Kg + hoff;
  const unsigned short* Vh = Vt + hoff;
  const int qw = qtB * 64 + w * 16;
  const unsigned int* mp = mPB + ((size_t)(qtB * 4 + w) * 2048 + lane) * 8;

  auto stage = [&](int s0, int buf) {
#pragma unroll
    for (int jj = 0; jj < 2; ++jj) {
      const int cq = jj * 256 + tid;
      const int r = cq >> 3, cc = cq & 7;
      const int cs = cc ^ (r & 7);
      GLOAD_LDS(Kh + (size_t)(s0 + r) * 64 + cs * 8,
                (char*)Ks[buf] + (jj * 256 + w * 64) * 16);
      GLOAD_LDS(Vh + (size_t)r * Tn + s0 + cs * 8,
                (char*)Vs[buf] + (jj * 256 + w * 64) * 16);
    }
  };

  // Q fragments (B-operand of swapped QK^T): Q[qw+lr][kk*32 + lg*8 + e]
  s8v qf[2];
#pragma unroll
  for (int kk = 0; kk < 2; ++kk)
    qf[kk] = *(const s8v*)(Qh + (size_t)(qw + lr) * 64 + kk * 32 + lg * 8);

  float lsum = 0.f;
  f4v oacc[4] = {};

  const int srcA = lr + ((lg & 1) << 5);
  const int srcB = srcA + 16;
  const int hi = lg >> 1;

  stage(0, 0);
  __syncthreads();

  for (int s0 = 0, t = 0; s0 < Tn; s0 += 64, ++t, mp += 512) {
    const int cur = t & 1;
    if (s0 + 64 < Tn) stage(s0 + 64, cur ^ 1);

    // C-init = packed bf16 mask (already *log2e)
    const uint4 u0 = *(const uint4*)(mp);
    const uint4 u1 = *(const uint4*)(mp + 4);
    const unsigned int wd[8] = {u0.x, u0.y, u0.z, u0.w, u1.x, u1.y, u1.z, u1.w};
    f4v scT[4];
#pragma unroll
    for (int n = 0; n < 4; ++n) {
      scT[n][0] = __uint_as_float(wd[2 * n] << 16);
      scT[n][1] = __uint_as_float(wd[2 * n] & 0xffff0000u);
      scT[n][2] = __uint_as_float(wd[2 * n + 1] << 16);
      scT[n][3] = __uint_as_float(wd[2 * n + 1] & 0xffff0000u);
    }

    // swapped QK^T from LDS
#pragma unroll
    for (int kk = 0; kk < 2; ++kk)
#pragma unroll
      for (int n = 0; n < 4; ++n) {
        const int row = n * 16 + lr;
        s8v kf = *(const s8v*)((const char*)Ks[cur] + row * 128 +
                               (((kk * 4 + lg) ^ (lr & 7)) << 4));
        scT[n] = MFMA16(kf, qf[kk], scT[n]);
      }

    // shift-free softmax numerator; row sum over 4 lanes (stride 16)
    float ssum = 0.f;
#pragma unroll
    for (int n = 0; n < 4; ++n)
#pragma unroll
      for (int rg = 0; rg < 4; ++rg) {
        const float p = EXP2(scT[n][rg]);
        scT[n][rg] = p;
        ssum += p;
      }
    ssum += __shfl_xor(ssum, 16);
    ssum += __shfl_xor(ssum, 32);
    lsum += ssum;

    // pack P^T to bf16 pair-words
    int pw0[4], pw1[4];
#pragma unroll
    for (int n = 0; n < 4; ++n) {
      pw0[n] = cvtpk(scT[n][0], scT[n][1]);
      pw1[n] = cvtpk(scT[n][2], scT[n][3]);
    }

    // PV: O += P * V (A-frag assembled via shfl, verified slot math)
#pragma unroll
    for (int kk = 0; kk < 2; ++kk) {
      const int a0 = __shfl(pw0[2 * kk], srcA), b0 = __shfl(pw0[2 * kk + 1], srcA);
      const int a1 = __shfl(pw1[2 * kk], srcA), b1 = __shfl(pw1[2 * kk + 1], srcA);
      const int a2 = __shfl(pw0[2 * kk], srcB), b2 = __shfl(pw0[2 * kk + 1], srcB);
      const int a3 = __shfl(pw1[2 * kk], srcB), b3 = __shfl(pw1[2 * kk + 1], srcB);
      union { s8v v; int x[4]; } pf;
      pf.x[0] = hi ? b0 : a0;
      pf.x[1] = hi ? b1 : a1;
      pf.x[2] = hi ? b2 : a2;
      pf.x[3] = hi ? b3 : a3;
#pragma unroll
      for (int n = 0; n < 4; ++n) {
        const int rd = n * 16 + lr;
        s8v vf = *(const s8v*)((const char*)Vs[cur] + rd * 128 +
                               (((kk * 4 + lg) ^ (lr & 7)) << 4));
        oacc[n] = MFMA16(pf.v, vf, oacc[n]);
      }
    }
    __syncthreads();  // drains next-tile stage + guards buffer reuse
  }

  // epilogue: O / lsum(q), write bf16 [B,T,H,D]
#pragma unroll
  for (int rg = 0; rg < 4; ++rg) {
    const float inv = 1.f / __shfl(lsum, lg * 4 + rg);
    const int t = qw + lg * 4 + rg;
#pragma unroll
    for (int n = 0; n < 4; ++n) {
      const int d = n * 16 + lr;
      Out[((size_t)(b * Tn + t) * Hn + h) * 64 + d] = f2bf(oacc[n][rg] * inv);
    }
  }
}

// ---------------------------------------------------------------------------
extern "C" void kernel_launch(void* const* d_in, const int* in_sizes, int n_in,
                              void* d_out, int out_size, void* d_ws, size_t ws_size,
                              hipStream_t stream) {
  (void)in_sizes; (void)n_in; (void)out_size; (void)ws_size;
  const float* query = (const float*)d_in[0];
  const float* key_  = (const float*)d_in[1];
  const float* value = (const float*)d_in[2];
  const float* mask  = (const float*)d_in[3];
  const float* Wq    = (const float*)d_in[4];
  const float* Wk    = (const float*)d_in[5];
  const float* Wv    = (const float*)d_in[6];
  const float* Wo    = (const float*)d_in[7];
  float* out = (float*)d_out;

  char* ws = (char*)d_ws;
  const size_t MB = 1024 * 1024;
  unsigned short* qx  = (unsigned short*)(ws + 0 * MB);   // [4096,1024] bf16 x3
  unsigned short* kx  = (unsigned short*)(ws + 8 * MB);
  unsigned short* vx  = (unsigned short*)(ws + 16 * MB);
  unsigned short* Qh  = (unsigned short*)(ws + 24 * MB);  // [B,H,T,D] (pre-scaled)
  unsigned short* Kh  = (unsigned short*)(ws + 32 * MB);  // [B,H,T,D]
  unsigned short* Vtg = (unsigned short*)(ws + 40 * MB);  // [B,H,D,S]
  unsigned short* atb = (unsigned short*)(ws + 48 * MB);  // [B,T,H,D]
  unsigned short* wqx = (unsigned short*)(ws + 56 * MB);  // 4x [1024,1024] bf16
  unsigned short* wkx = (unsigned short*)(ws + 58 * MB);
  unsigned short* wvx = (unsigned short*)(ws + 60 * MB);
  unsigned short* wox = (unsigned short*)(ws + 62 * MB);
  unsigned int* mPB = (unsigned int*)(ws + 0 * MB);  // overlays dead qx

  const int nBig = Bn * Tn * En / 8;   // 524288
  const int nW   = En * En / 8;        // 131072
  cast7_kernel<<<2560, 256, 0, stream>>>(query, key_, value, Wq, Wk, Wv, Wo,
                                         qx, wqx, nBig, nW);

  gemm3_kernel<<<768, 256, 0, stream>>>(qx, kx, vx, wqx, wkx, wvx, Qh, Kh, Vtg);

  maskpack_kernel<<<dim3(128, 32), 64, 0, stream>>>(mask, mPB);

  attn_kernel<<<1024, 256, 0, stream>>>(Qh, Kh, Vtg, mPB, atb);

  gemm_out<<<dim3(8, 32), 256, 0, stream>>>(atb, wox, out);
}